// Round 11
// baseline (80.261 us; speedup 1.0000x reference)
//
#include <hip/hip_runtime.h>

// RoIAlign dense (11x11 bilinear) + 3x3/s2 max pool -> [K=2048, C=256, 5, 5]
// features: [B=4, C=256, H=100, W=100] f32 (NCHW), rois: [K,5] f32
//
// Ladder: R2 45 -> R5 42 main (f32 static SGPR) -> R8 ~34 main (bf16
// (c,c+128)-pair dword loads, 2-wave/roi) -> R9 40.7 (ushort loads: 2x VMEM
// instr, bad) -> R10 57.8 (launch_bounds(128,6) pinned VGPR=40, killed load
// ILP; VALUBusy 22%). Lessons: keep VGPR >= ~80 for the 44-load batches;
// grid gives only 8 blocks/CU, so waves/CU was 16 in R8.
// R11: row-split 4-wave blocks. 256 thr = 1 roi; wave = (half, rowgroup):
//   rg0: rows 0-4 -> ph0,ph1   rg1: rows 4-10 -> ph2,ph3,ph4
// (row 4 duplicated; each ph owned by one wave -> no merge). Pooled f32x2
// results written to a block f32 stage (== output layout), one barrier,
// bulk coalesced copy. pk f32x2 lerps. No VGPR pin.

constexpr int Bn = 4, Cn = 256, Hn = 100, Wn = 100;
constexpr int HWn = Hn * Wn;
constexpr int PAIRS = Cn / 2;            // 128 channel pairs
constexpr float SCALE = 0.0625f;

typedef float f32x2 __attribute__((ext_vector_type(2)));

__device__ __forceinline__ unsigned int bfpack(float a, float b) {
    // RTNE f32->bf16, pack (a -> low16, b -> high16). Inputs finite.
    unsigned int ua = __float_as_uint(a), ub = __float_as_uint(b);
    ua = (ua + 0x7FFFu + ((ua >> 16) & 1u)) >> 16;
    ub = (ub + 0x7FFFu + ((ub >> 16) & 1u)) & 0xFFFF0000u;
    return ua | ub;
}
__device__ __forceinline__ f32x2 unp(unsigned int u) {
    f32x2 r;
    r.x = __uint_as_float(u << 16);          // low  channel (c)
    r.y = __uint_as_float(u & 0xFFFF0000u);  // high channel (c+128)
    return r;
}
__device__ __forceinline__ f32x2 vmax2(f32x2 a, f32x2 b) {
    f32x2 r; r.x = fmaxf(a.x, b.x); r.y = fmaxf(a.y, b.y); return r;
}

// ------- Kernel 1: NCHW f32 -> NHWC bf16 (c, c+128)-pair (u32) transpose -------
__global__ __launch_bounds__(256)
void nchw_to_nhwc_bf16(const float* __restrict__ in, unsigned int* __restrict__ out)
{
    __shared__ float tile[64][65];
    const int s0 = blockIdx.x * 64;
    const int p0 = blockIdx.y * 32;          // pair-tile base (0,32,64,96)
    const int b  = blockIdx.z;
    const int t  = threadIdx.x;

    {   // load: thread -> tile row, 4 consecutive spatial (dwordx4)
        const int cl = t >> 4;               // 0..15
        const int s4 = (t & 15) * 4;         // 0..60
        const float* ip = in + (size_t)b * Cn * HWn + s0;
#pragma unroll
        for (int pass = 0; pass < 4; ++pass) {
            const int r  = pass * 16 + cl;   // tile row 0..63
            const int ch = (pass < 2) ? (p0 + r) : (p0 + 96 + r);  // +128 for hi half
            if (s0 + s4 + 3 < HWn) {
                const float4 v = *(const float4*)(ip + (size_t)ch * HWn + s4);
                tile[r][s4 + 0] = v.x; tile[r][s4 + 1] = v.y;
                tile[r][s4 + 2] = v.z; tile[r][s4 + 3] = v.w;
            } else {
#pragma unroll
                for (int i = 0; i < 4; ++i)
                    tile[r][s4 + i] = (s0 + s4 + i < HWn) ? ip[(size_t)ch * HWn + s4 + i] : 0.0f;
            }
        }
    }
    __syncthreads();
    {   // store: thread -> spatial s, uint2 = pairs (p0+li, p0+li+1)
        const int s = t >> 2;                // 0..63
        const int q = t & 3;
        if (s0 + s < HWn) {
            unsigned int* op = out + ((size_t)b * HWn + (s0 + s)) * PAIRS + p0;
#pragma unroll
            for (int i = 0; i < 4; ++i) {
                const int li = q * 2 + i * 8;            // even, 0..30
                uint2 v;
                v.x = bfpack(tile[li    ][s], tile[li + 32][s]);  // pair p0+li
                v.y = bfpack(tile[li + 1][s], tile[li + 33][s]);  // pair p0+li+1
                *(uint2*)(op + li) = v;
            }
        }
    }
}

// ------- Kernel 2: RoIAlign+pool, 4 waves = (channel half) x (row group) -------
__global__ __launch_bounds__(256)
void roipool_split(const unsigned int* __restrict__ f, const float* __restrict__ rois,
                   float* __restrict__ out)
{
    __shared__ float stage[Cn * 25];          // 25.6 KB, == output layout for roi k
    const int tid  = threadIdx.x;
    const int wid  = tid >> 6;
    const int lane = tid & 63;
    const int half = wid & 1;                 // channel half
    const int rg   = wid >> 1;                // row group
    const int k    = blockIdx.x;

    const float x1 = rois[k * 5 + 1] * SCALE;
    const float y1 = rois[k * 5 + 2] * SCALE;
    const float x2 = rois[k * 5 + 3] * SCALE;
    const float y2 = rois[k * 5 + 4] * SCALE;
    const int   b  = __builtin_amdgcn_readfirstlane((int)rois[k * 5 + 0]);

    const int pi = half * 64 + lane;          // pair index 0..127
    const unsigned int* fb = f + (size_t)b * HWn * PAIRS;

    // per-roi x-tap metadata: element offsets as SGPRs, weights per-lane
    int   xo0[11], xo1[11];
    float wx[11];
#pragma unroll
    for (int j = 0; j < 11; ++j) {
        const float xs  = x1 + (x2 - x1) * ((float)j * 0.1f);
        const float x0f = floorf(xs);
        wx[j] = xs - x0f;                     // weight from UNCLIPPED coord
        const int x0i = (int)x0f;
        xo0[j] = __builtin_amdgcn_readfirstlane(min(max(x0i,     0), Wn - 1)) * PAIRS;
        xo1[j] = __builtin_amdgcn_readfirstlane(min(max(x0i + 1, 0), Wn - 1)) * PAIRS;
    }

    // one dense sample row gy -> 5 x-window maxes (both channels, packed f32)
    auto dorow = [&](int gy, f32x2 (&dst)[5]) {
        const float ys  = y1 + (y2 - y1) * ((float)gy * 0.1f);
        const float y0f = floorf(ys);
        const float wy  = ys - y0f;
        const int   y0i = (int)y0f;
        const int r0 = __builtin_amdgcn_readfirstlane(min(max(y0i,     0), Hn - 1));
        const int r1 = __builtin_amdgcn_readfirstlane(min(max(y0i + 1, 0), Hn - 1));
        const unsigned int* rp0 = fb + (size_t)(r0 * Wn) * PAIRS;
        const unsigned int* rp1 = fb + (size_t)(r1 * Wn) * PAIRS;
#pragma unroll
        for (int j = 0; j < 11; ++j) {
            const unsigned int u00 = (rp0 + xo0[j])[pi];   // uniform ptr + lane idx
            const unsigned int u01 = (rp0 + xo1[j])[pi];
            const unsigned int u10 = (rp1 + xo0[j])[pi];
            const unsigned int u11 = (rp1 + xo1[j])[pi];
            const f32x2 t00 = unp(u00);
            const f32x2 t01 = unp(u01);
            const f32x2 t10 = unp(u10);
            const f32x2 t11 = unp(u11);
            const f32x2 X0 = t00 + wx[j] * (t01 - t00);
            const f32x2 X1 = t10 + wx[j] * (t11 - t10);
            const f32x2 s  = X0 + wy    * (X1 - X0);
            if (j == 0)      { dst[0] = s; }
            else if (j & 1)  { dst[j >> 1] = vmax2(dst[j >> 1], s); }
            else {
                dst[(j >> 1) - 1] = vmax2(dst[(j >> 1) - 1], s);
                if (j < 10) dst[j >> 1] = s;
            }
        }
    };

    // write one pooled ph row (max of three dense rows) for both channels
    auto wrph = [&](int ph, const f32x2 (&a)[5], const f32x2 (&b_)[5], const f32x2 (&c)[5]) {
#pragma unroll
        for (int pw = 0; pw < 5; ++pw) {
            const f32x2 m = vmax2(vmax2(a[pw], b_[pw]), c[pw]);
            stage[pi * 25 + ph * 5 + pw]           = m.x;   // ch pi
            stage[(pi + 128) * 25 + ph * 5 + pw]   = m.y;   // ch pi+128
        }
    };

    f32x2 a[5], b2[5], c[5];
    if (rg == 0) {                            // rows 0..4 -> ph0, ph1
        dorow(0, a); dorow(1, b2); dorow(2, c);
        wrph(0, a, b2, c);
        dorow(3, a); dorow(4, b2);
        wrph(1, c, a, b2);
    } else {                                  // rows 4..10 -> ph2, ph3, ph4
        dorow(4, a); dorow(5, b2); dorow(6, c);
        wrph(2, a, b2, c);
        dorow(7, a); dorow(8, b2);
        wrph(3, c, a, b2);
        dorow(9, c); dorow(10, a);
        wrph(4, b2, c, a);
    }

    __syncthreads();

    // bulk coalesced copy: stage layout == output layout for this roi
    float* ob = out + (size_t)k * (Cn * 25);
#pragma unroll
    for (int i = 0; i < 25; ++i)
        ob[i * 256 + tid] = stage[i * 256 + tid];
}

// ------------- Fallback (reads NCHW directly) if workspace too small -------------
__global__ __launch_bounds__(256)
void roialign_pool_fallback(const float* __restrict__ feats,
                            const float* __restrict__ rois,
                            float* __restrict__ out)
{
    __shared__ float smem[4][2][128];
    const int k    = blockIdx.x;
    const int tid  = threadIdx.x;
    const int wid  = tid >> 6;
    const int lane = tid & 63;

    const float x1 = rois[k * 5 + 1] * SCALE;
    const float y1 = rois[k * 5 + 2] * SCALE;
    const float x2 = rois[k * 5 + 3] * SCALE;
    const float y2 = rois[k * 5 + 4] * SCALE;
    const int   b  = (int)rois[k * 5 + 0];

    const int  p1   = 64 + lane;
    const bool act1 = (p1 < 121);
    int   o00[2], o01[2], o10[2], o11[2];
    float w00[2], w01[2], w10[2], w11[2];
#pragma unroll
    for (int r = 0; r < 2; ++r) {
        const int p  = (r == 0) ? lane : (act1 ? p1 : 120);
        const int gy = p / 11;
        const int gx = p - gy * 11;
        const float ys = y1 + (y2 - y1) * ((float)gy / 10.0f);
        const float xs = x1 + (x2 - x1) * ((float)gx / 10.0f);
        const float y0f = floorf(ys), x0f = floorf(xs);
        const float wy = ys - y0f, wxx = xs - x0f;
        const int y0i = (int)y0f, x0i = (int)x0f;
        const int y0c = min(max(y0i, 0), Hn - 1), y1c = min(max(y0i + 1, 0), Hn - 1);
        const int x0c = min(max(x0i, 0), Wn - 1), x1c = min(max(x0i + 1, 0), Wn - 1);
        o00[r] = y0c * Wn + x0c; o01[r] = y0c * Wn + x1c;
        o10[r] = y1c * Wn + x0c; o11[r] = y1c * Wn + x1c;
        w00[r] = (1.0f - wy) * (1.0f - wxx); w01[r] = (1.0f - wy) * wxx;
        w10[r] = wy * (1.0f - wxx);          w11[r] = wy * wxx;
    }
    const bool pool  = (lane < 25);
    const int  ph    = lane / 5;
    const int  pw    = lane - ph * 5;
    const int  pbase = (2 * ph) * 11 + 2 * pw;
    const float* base = feats + ((size_t)b * Cn + (size_t)wid * 64) * HWn;
    float*       op   = out + ((size_t)k * Cn + (size_t)wid * 64) * 25 + lane;
    for (int it = 0; it < 64; ++it) {
        const float* ff  = base + (size_t)it * HWn;
        float*       buf = smem[wid][it & 1];
        const float v0 = ff[o00[0]] * w00[0] + ff[o01[0]] * w01[0]
                       + ff[o10[0]] * w10[0] + ff[o11[0]] * w11[0];
        const float v1 = ff[o00[1]] * w00[1] + ff[o01[1]] * w01[1]
                       + ff[o10[1]] * w10[1] + ff[o11[1]] * w11[1];
        buf[lane] = v0;
        if (act1) buf[p1] = v1;
        if (pool) {
            float m =          buf[pbase +  0];
            m = fmaxf(m, buf[pbase +  1]);
            m = fmaxf(m, buf[pbase +  2]);
            m = fmaxf(m, buf[pbase + 11]);
            m = fmaxf(m, buf[pbase + 12]);
            m = fmaxf(m, buf[pbase + 13]);
            m = fmaxf(m, buf[pbase + 22]);
            m = fmaxf(m, buf[pbase + 23]);
            m = fmaxf(m, buf[pbase + 24]);
            op[it * 25] = m;
        }
    }
}

extern "C" void kernel_launch(void* const* d_in, const int* in_sizes, int n_in,
                              void* d_out, int out_size, void* d_ws, size_t ws_size,
                              hipStream_t stream) {
    const float* feats = (const float*)d_in[0];
    const float* rois  = (const float*)d_in[1];
    float*       out   = (float*)d_out;
    const int K = in_sizes[1] / 5;                                  // 2048
    const size_t need = (size_t)Bn * HWn * PAIRS * sizeof(unsigned int);  // 20.48 MB

    if (ws_size >= need) {
        unsigned int* nhwc = (unsigned int*)d_ws;
        dim3 tgrid((HWn + 63) / 64, PAIRS / 32, Bn);                // 157 x 4 x 4
        nchw_to_nhwc_bf16<<<tgrid, 256, 0, stream>>>(feats, nhwc);
        roipool_split<<<K, 256, 0, stream>>>(nhwc, rois, out);
    } else {
        roialign_pool_fallback<<<K, 256, 0, stream>>>(feats, rois, out);
    }
}

// Round 12
// 47.320 us; speedup vs baseline: 1.6961x; 1.6961x over previous
//
#include <hip/hip_runtime.h>

// RoIAlign dense (11x11 bilinear) + 3x3/s2 max pool -> [K=2048, C=256, 5, 5]
// features: [B=4, C=256, H=100, W=100] f32 (NCHW), rois: [K,5] f32
//
// Ladder: R2 45 -> R5 42 main (f32 static SGPR) -> R8 ~34 main (bf16
// (c,c+128)-pair dword loads, 2 waves/roi, 16 waves/CU) -> R9 40.7 (ushort:
// 2x VMEM instr) -> R10/R11 (f32x2 packed math: VGPR 40, VALUBusy 22%,
// latency-bound BOTH times -> RULE: scalar f32 math only).
// R12 = R11's row-split structure + R8's scalar dorow:
//   256-thr block = 1 roi; wave (half, rg): rg0 rows 0-4 -> ph0,ph1;
//   rg1 rows 4-10 -> ph2..ph4. Each wave owns disjoint (ch, ph) stage region;
//   one barrier; bulk coalesced copy. 24 waves/CU (vs R8's 16), same MLP.

constexpr int Bn = 4, Cn = 256, Hn = 100, Wn = 100;
constexpr int HWn = Hn * Wn;
constexpr int PAIRS = Cn / 2;            // 128 channel pairs
constexpr float SCALE = 0.0625f;

__device__ __forceinline__ unsigned int bfpack(float a, float b) {
    // RTNE f32->bf16, pack (a -> low16, b -> high16). Inputs finite.
    unsigned int ua = __float_as_uint(a), ub = __float_as_uint(b);
    ua = (ua + 0x7FFFu + ((ua >> 16) & 1u)) >> 16;
    ub = (ub + 0x7FFFu + ((ub >> 16) & 1u)) & 0xFFFF0000u;
    return ua | ub;
}

// ------- Kernel 1: NCHW f32 -> NHWC bf16 (c, c+128)-pair (u32) transpose -------
__global__ __launch_bounds__(256)
void nchw_to_nhwc_bf16(const float* __restrict__ in, unsigned int* __restrict__ out)
{
    __shared__ float tile[64][65];
    const int s0 = blockIdx.x * 64;
    const int p0 = blockIdx.y * 32;          // pair-tile base (0,32,64,96)
    const int b  = blockIdx.z;
    const int t  = threadIdx.x;

    {   // load: thread -> tile row, 4 consecutive spatial (dwordx4)
        const int cl = t >> 4;               // 0..15
        const int s4 = (t & 15) * 4;         // 0..60
        const float* ip = in + (size_t)b * Cn * HWn + s0;
#pragma unroll
        for (int pass = 0; pass < 4; ++pass) {
            const int r  = pass * 16 + cl;   // tile row 0..63
            const int ch = (pass < 2) ? (p0 + r) : (p0 + 96 + r);  // +128 for hi half
            if (s0 + s4 + 3 < HWn) {
                const float4 v = *(const float4*)(ip + (size_t)ch * HWn + s4);
                tile[r][s4 + 0] = v.x; tile[r][s4 + 1] = v.y;
                tile[r][s4 + 2] = v.z; tile[r][s4 + 3] = v.w;
            } else {
#pragma unroll
                for (int i = 0; i < 4; ++i)
                    tile[r][s4 + i] = (s0 + s4 + i < HWn) ? ip[(size_t)ch * HWn + s4 + i] : 0.0f;
            }
        }
    }
    __syncthreads();
    {   // store: thread -> spatial s, uint2 = pairs (p0+li, p0+li+1)
        const int s = t >> 2;                // 0..63
        const int q = t & 3;
        if (s0 + s < HWn) {
            unsigned int* op = out + ((size_t)b * HWn + (s0 + s)) * PAIRS + p0;
#pragma unroll
            for (int i = 0; i < 4; ++i) {
                const int li = q * 2 + i * 8;            // even, 0..30
                uint2 v;
                v.x = bfpack(tile[li    ][s], tile[li + 32][s]);  // pair p0+li
                v.y = bfpack(tile[li + 1][s], tile[li + 33][s]);  // pair p0+li+1
                *(uint2*)(op + li) = v;
            }
        }
    }
}

// ------- Kernel 2: RoIAlign+pool, 4 waves = (channel half) x (row group) -------
__global__ __launch_bounds__(256)
void roipool_split(const unsigned int* __restrict__ f, const float* __restrict__ rois,
                   float* __restrict__ out)
{
    __shared__ float stage[Cn * 25];          // 25.6 KB, == output layout for roi k
    const int tid  = threadIdx.x;
    const int wid  = tid >> 6;
    const int lane = tid & 63;
    const int half = wid & 1;                 // channel half
    const int rg   = wid >> 1;                // row group (wave-uniform)
    const int k    = blockIdx.x;

    const float x1 = rois[k * 5 + 1] * SCALE;
    const float y1 = rois[k * 5 + 2] * SCALE;
    const float x2 = rois[k * 5 + 3] * SCALE;
    const float y2 = rois[k * 5 + 4] * SCALE;
    const int   b  = __builtin_amdgcn_readfirstlane((int)rois[k * 5 + 0]);

    const int pi = half * 64 + lane;          // pair index 0..127
    const unsigned int* fb = f + (size_t)b * HWn * PAIRS;

    // per-roi x-tap metadata: element offsets as SGPRs, weights per-lane
    int   xo0[11], xo1[11];
    float wx[11];
#pragma unroll
    for (int j = 0; j < 11; ++j) {
        const float xs  = x1 + (x2 - x1) * ((float)j * 0.1f);
        const float x0f = floorf(xs);
        wx[j] = xs - x0f;                     // weight from UNCLIPPED coord
        const int x0i = (int)x0f;
        xo0[j] = __builtin_amdgcn_readfirstlane(min(max(x0i,     0), Wn - 1)) * PAIRS;
        xo1[j] = __builtin_amdgcn_readfirstlane(min(max(x0i + 1, 0), Wn - 1)) * PAIRS;
    }

    // one dense sample row gy -> 5 x-window maxes, both channels, SCALAR math
    auto dorow = [&](int gy, float (&dlo)[5], float (&dhi)[5]) {
        const float ys  = y1 + (y2 - y1) * ((float)gy * 0.1f);
        const float y0f = floorf(ys);
        const float wy  = ys - y0f;
        const int   y0i = (int)y0f;
        const int r0 = __builtin_amdgcn_readfirstlane(min(max(y0i,     0), Hn - 1));
        const int r1 = __builtin_amdgcn_readfirstlane(min(max(y0i + 1, 0), Hn - 1));
        const unsigned int* rp0 = fb + (size_t)(r0 * Wn) * PAIRS;
        const unsigned int* rp1 = fb + (size_t)(r1 * Wn) * PAIRS;
#pragma unroll
        for (int j = 0; j < 11; ++j) {
            const unsigned int u00 = (rp0 + xo0[j])[pi];   // uniform ptr + lane idx
            const unsigned int u01 = (rp0 + xo1[j])[pi];
            const unsigned int u10 = (rp1 + xo0[j])[pi];
            const unsigned int u11 = (rp1 + xo1[j])[pi];
            // low channel (bits 15:0 -> shl 16)
            const float a00 = __uint_as_float(u00 << 16);
            const float a01 = __uint_as_float(u01 << 16);
            const float a10 = __uint_as_float(u10 << 16);
            const float a11 = __uint_as_float(u11 << 16);
            float X0 = a00 + wx[j] * (a01 - a00);
            float X1 = a10 + wx[j] * (a11 - a10);
            const float sl = X0 + wy * (X1 - X0);
            // high channel (bits 31:16 -> mask)
            const float b00 = __uint_as_float(u00 & 0xFFFF0000u);
            const float b01 = __uint_as_float(u01 & 0xFFFF0000u);
            const float b10 = __uint_as_float(u10 & 0xFFFF0000u);
            const float b11 = __uint_as_float(u11 & 0xFFFF0000u);
            X0 = b00 + wx[j] * (b01 - b00);
            X1 = b10 + wx[j] * (b11 - b10);
            const float sh = X0 + wy * (X1 - X0);
            if (j == 0)      { dlo[0] = sl; dhi[0] = sh; }
            else if (j & 1)  { dlo[j >> 1] = fmaxf(dlo[j >> 1], sl);
                               dhi[j >> 1] = fmaxf(dhi[j >> 1], sh); }
            else {
                dlo[(j >> 1) - 1] = fmaxf(dlo[(j >> 1) - 1], sl);
                dhi[(j >> 1) - 1] = fmaxf(dhi[(j >> 1) - 1], sh);
                if (j < 10) { dlo[j >> 1] = sl; dhi[j >> 1] = sh; }
            }
        }
    };

    // write one pooled ph row (max of three dense rows) for both channels
    auto wrph = [&](int ph, const float (&al)[5], const float (&ah)[5],
                            const float (&bl)[5], const float (&bh)[5],
                            const float (&cl)[5], const float (&ch)[5]) {
#pragma unroll
        for (int pw = 0; pw < 5; ++pw) {
            stage[pi * 25 + ph * 5 + pw]         = fmaxf(fmaxf(al[pw], bl[pw]), cl[pw]);
            stage[(pi + 128) * 25 + ph * 5 + pw] = fmaxf(fmaxf(ah[pw], bh[pw]), ch[pw]);
        }
    };

    float alo[5], ahi[5], blo[5], bhi[5], clo[5], chi[5];
    if (rg == 0) {                            // rows 0..4 -> ph0, ph1
        dorow(0, alo, ahi); dorow(1, blo, bhi); dorow(2, clo, chi);
        wrph(0, alo, ahi, blo, bhi, clo, chi);
        dorow(3, alo, ahi); dorow(4, blo, bhi);
        wrph(1, clo, chi, alo, ahi, blo, bhi);
    } else {                                  // rows 4..10 -> ph2, ph3, ph4
        dorow(4, alo, ahi); dorow(5, blo, bhi); dorow(6, clo, chi);
        wrph(2, alo, ahi, blo, bhi, clo, chi);
        dorow(7, alo, ahi); dorow(8, blo, bhi);
        wrph(3, clo, chi, alo, ahi, blo, bhi);
        dorow(9, clo, chi); dorow(10, alo, ahi);
        wrph(4, blo, bhi, clo, chi, alo, ahi);
    }

    __syncthreads();

    // bulk coalesced copy: stage layout == output layout for this roi
    float* ob = out + (size_t)k * (Cn * 25);
#pragma unroll
    for (int i = 0; i < 25; ++i)
        ob[i * 256 + tid] = stage[i * 256 + tid];
}

// ------------- Fallback (reads NCHW directly) if workspace too small -------------
__global__ __launch_bounds__(256)
void roialign_pool_fallback(const float* __restrict__ feats,
                            const float* __restrict__ rois,
                            float* __restrict__ out)
{
    __shared__ float smem[4][2][128];
    const int k    = blockIdx.x;
    const int tid  = threadIdx.x;
    const int wid  = tid >> 6;
    const int lane = tid & 63;

    const float x1 = rois[k * 5 + 1] * SCALE;
    const float y1 = rois[k * 5 + 2] * SCALE;
    const float x2 = rois[k * 5 + 3] * SCALE;
    const float y2 = rois[k * 5 + 4] * SCALE;
    const int   b  = (int)rois[k * 5 + 0];

    const int  p1   = 64 + lane;
    const bool act1 = (p1 < 121);
    int   o00[2], o01[2], o10[2], o11[2];
    float w00[2], w01[2], w10[2], w11[2];
#pragma unroll
    for (int r = 0; r < 2; ++r) {
        const int p  = (r == 0) ? lane : (act1 ? p1 : 120);
        const int gy = p / 11;
        const int gx = p - gy * 11;
        const float ys = y1 + (y2 - y1) * ((float)gy / 10.0f);
        const float xs = x1 + (x2 - x1) * ((float)gx / 10.0f);
        const float y0f = floorf(ys), x0f = floorf(xs);
        const float wy = ys - y0f, wxx = xs - x0f;
        const int y0i = (int)y0f, x0i = (int)x0f;
        const int y0c = min(max(y0i, 0), Hn - 1), y1c = min(max(y0i + 1, 0), Hn - 1);
        const int x0c = min(max(x0i, 0), Wn - 1), x1c = min(max(x0i + 1, 0), Wn - 1);
        o00[r] = y0c * Wn + x0c; o01[r] = y0c * Wn + x1c;
        o10[r] = y1c * Wn + x0c; o11[r] = y1c * Wn + x1c;
        w00[r] = (1.0f - wy) * (1.0f - wxx); w01[r] = (1.0f - wy) * wxx;
        w10[r] = wy * (1.0f - wxx);          w11[r] = wy * wxx;
    }
    const bool pool  = (lane < 25);
    const int  ph    = lane / 5;
    const int  pw    = lane - ph * 5;
    const int  pbase = (2 * ph) * 11 + 2 * pw;
    const float* base = feats + ((size_t)b * Cn + (size_t)wid * 64) * HWn;
    float*       op   = out + ((size_t)k * Cn + (size_t)wid * 64) * 25 + lane;
    for (int it = 0; it < 64; ++it) {
        const float* ff  = base + (size_t)it * HWn;
        float*       buf = smem[wid][it & 1];
        const float v0 = ff[o00[0]] * w00[0] + ff[o01[0]] * w01[0]
                       + ff[o10[0]] * w10[0] + ff[o11[0]] * w11[0];
        const float v1 = ff[o00[1]] * w00[1] + ff[o01[1]] * w01[1]
                       + ff[o10[1]] * w10[1] + ff[o11[1]] * w11[1];
        buf[lane] = v0;
        if (act1) buf[p1] = v1;
        if (pool) {
            float m =          buf[pbase +  0];
            m = fmaxf(m, buf[pbase +  1]);
            m = fmaxf(m, buf[pbase +  2]);
            m = fmaxf(m, buf[pbase + 11]);
            m = fmaxf(m, buf[pbase + 12]);
            m = fmaxf(m, buf[pbase + 13]);
            m = fmaxf(m, buf[pbase + 22]);
            m = fmaxf(m, buf[pbase + 23]);
            m = fmaxf(m, buf[pbase + 24]);
            op[it * 25] = m;
        }
    }
}

extern "C" void kernel_launch(void* const* d_in, const int* in_sizes, int n_in,
                              void* d_out, int out_size, void* d_ws, size_t ws_size,
                              hipStream_t stream) {
    const float* feats = (const float*)d_in[0];
    const float* rois  = (const float*)d_in[1];
    float*       out   = (float*)d_out;
    const int K = in_sizes[1] / 5;                                  // 2048
    const size_t need = (size_t)Bn * HWn * PAIRS * sizeof(unsigned int);  // 20.48 MB

    if (ws_size >= need) {
        unsigned int* nhwc = (unsigned int*)d_ws;
        dim3 tgrid((HWn + 63) / 64, PAIRS / 32, Bn);                // 157 x 4 x 4
        nchw_to_nhwc_bf16<<<tgrid, 256, 0, stream>>>(feats, nhwc);
        roipool_split<<<K, 256, 0, stream>>>(nhwc, rois, out);
    } else {
        roialign_pool_fallback<<<K, 256, 0, stream>>>(feats, rois, out);
    }
}

// Round 14
// 42.497 us; speedup vs baseline: 1.8886x; 1.1135x over previous
//
#include <hip/hip_runtime.h>
#include <hip/hip_fp16.h>

// RoIAlign dense (11x11 bilinear) + 3x3/s2 max pool -> [K=2048, C=256, 5, 5]
// features: [B=4, C=256, H=100, W=100] f32 (NCHW), rois: [K,5] f32
//
// Ladder: R2 45 -> R5 42 main (f32 scalar, static SGPR) -> R8 ~34 main (bf16
// (c,c+128)-pair dword loads, 2-wave/roi) -> R9-R12 established: VMEM instr
// count matters (~2cy each), f32x2 packed math = codegen collapse (2x), and
// at ~34us the kernel is ~75% VALU-bound (unpack + scalar lerps).
// R13/R14: f16 instead of bf16 -> loaded u32 IS a __half2: no unpack at all;
// lerps run packed via __hfma2/__hsub2 (v_pk_fma_f16), max via inline-asm
// v_pk_max_f16 (ROCm 7.2 lacks __hmax2 -- R13 compile fail, fixed here).
// Structure identical to R8 (best measured): 128-thr block = 1 roi, wave =
// channel half, 44 dword loads per dense row, pooled o2[25] half2 in regs,
// two-phase LDS stage, bulk coalesced copy (every 64B line written once).
// Precision: f16 RTNE (10-bit mantissa) BEATS bf16: absmax should drop.

constexpr int Bn = 4, Cn = 256, Hn = 100, Wn = 100;
constexpr int HWn = Hn * Wn;
constexpr int PAIRS = Cn / 2;            // 128 channel pairs
constexpr float SCALE = 0.0625f;

__device__ __forceinline__ unsigned int hpack(float a, float b) {
    // RTNE f32->f16, pack (a -> low16, b -> high16)
    const __half2 h = __halves2half2(__float2half_rn(a), __float2half_rn(b));
    return *reinterpret_cast<const unsigned int*>(&h);
}

__device__ __forceinline__ __half2 hmax2(__half2 a, __half2 b) {
    // ROCm 7.2 has no __hmax2; emit the VOP3P packed max directly.
    unsigned int ua = *reinterpret_cast<unsigned int*>(&a);
    unsigned int ub = *reinterpret_cast<unsigned int*>(&b);
    unsigned int ur;
    asm("v_pk_max_f16 %0, %1, %2" : "=v"(ur) : "v"(ua), "v"(ub));
    return *reinterpret_cast<__half2*>(&ur);
}

// ------- Kernel 1: NCHW f32 -> NHWC f16 (c, c+128)-pair (u32) transpose -------
// blockIdx.y covers 32 pairs: pairs p0..p0+31 = channels {p0+r, p0+r+128}.
__global__ __launch_bounds__(256)
void nchw_to_nhwc_f16(const float* __restrict__ in, unsigned int* __restrict__ out)
{
    __shared__ float tile[64][65];           // rows 0..31: ch p0+r; 32..63: ch p0+128+(r-32)
    const int s0 = blockIdx.x * 64;
    const int p0 = blockIdx.y * 32;          // pair-tile base (0,32,64,96)
    const int b  = blockIdx.z;
    const int t  = threadIdx.x;

    {   // load: thread -> tile row, 4 consecutive spatial (dwordx4)
        const int cl = t >> 4;               // 0..15
        const int s4 = (t & 15) * 4;         // 0..60
        const float* ip = in + (size_t)b * Cn * HWn + s0;
#pragma unroll
        for (int pass = 0; pass < 4; ++pass) {
            const int r  = pass * 16 + cl;   // tile row 0..63
            const int ch = (pass < 2) ? (p0 + r) : (p0 + 96 + r);  // +128 for hi half
            if (s0 + s4 + 3 < HWn) {
                const float4 v = *(const float4*)(ip + (size_t)ch * HWn + s4);
                tile[r][s4 + 0] = v.x; tile[r][s4 + 1] = v.y;
                tile[r][s4 + 2] = v.z; tile[r][s4 + 3] = v.w;
            } else {
#pragma unroll
                for (int i = 0; i < 4; ++i)
                    tile[r][s4 + i] = (s0 + s4 + i < HWn) ? ip[(size_t)ch * HWn + s4 + i] : 0.0f;
            }
        }
    }
    __syncthreads();
    {   // store: thread -> spatial s, uint2 = pairs (p0+li, p0+li+1)
        const int s = t >> 2;                // 0..63
        const int q = t & 3;
        if (s0 + s < HWn) {
            unsigned int* op = out + ((size_t)b * HWn + (s0 + s)) * PAIRS + p0;
#pragma unroll
            for (int i = 0; i < 4; ++i) {
                const int li = q * 2 + i * 8;            // even, 0..30
                uint2 v;
                v.x = hpack(tile[li    ][s], tile[li + 32][s]);  // pair p0+li
                v.y = hpack(tile[li + 1][s], tile[li + 33][s]);  // pair p0+li+1
                *(uint2*)(op + li) = v;
            }
        }
    }
}

// ------- Kernel 2: RoIAlign+pool, lane = channel pair, packed f16 math -------
// 128-thread block = 1 roi; wave wid = channel half (pairs wid*64..+63 =
// channels wid*64..+63 lo, +128 hi). Stage 1600 floats/wave = 12.8 KB.
__global__ __launch_bounds__(128)
void roipool_half(const __half2* __restrict__ f, const float* __restrict__ rois,
                  float* __restrict__ out)
{
    __shared__ float stage[2][1600];          // [wave][64ch x 25], 12.8 KB
    const int tid  = threadIdx.x;
    const int wid  = tid >> 6;                // channel half
    const int lane = tid & 63;
    const int k    = blockIdx.x;

    const float x1 = rois[k * 5 + 1] * SCALE;
    const float y1 = rois[k * 5 + 2] * SCALE;
    const float x2 = rois[k * 5 + 3] * SCALE;
    const float y2 = rois[k * 5 + 4] * SCALE;
    const int   b  = __builtin_amdgcn_readfirstlane((int)rois[k * 5 + 0]);

    const int pi = wid * 64 + lane;           // pair index 0..127
    const __half2* fb = f + (size_t)b * HWn * PAIRS;

    // per-roi x-tap metadata: element offsets as SGPRs, weights as half2
    int     xo0[11], xo1[11];
    __half2 wxh[11];
#pragma unroll
    for (int j = 0; j < 11; ++j) {
        const float xs  = x1 + (x2 - x1) * ((float)j * 0.1f);
        const float x0f = floorf(xs);
        wxh[j] = __float2half2_rn(xs - x0f);  // weight from UNCLIPPED coord
        const int x0i = (int)x0f;
        xo0[j] = __builtin_amdgcn_readfirstlane(min(max(x0i,     0), Wn - 1)) * PAIRS;
        xo1[j] = __builtin_amdgcn_readfirstlane(min(max(x0i + 1, 0), Wn - 1)) * PAIRS;
    }

    // one dense sample row gy -> 5 x-window maxes, both channels packed f16
    auto dorow = [&](int gy, __half2 (&dst)[5]) {
        const float ys  = y1 + (y2 - y1) * ((float)gy * 0.1f);
        const float y0f = floorf(ys);
        const __half2 wyh = __float2half2_rn(ys - y0f);
        const int   y0i = (int)y0f;
        const int r0 = __builtin_amdgcn_readfirstlane(min(max(y0i,     0), Hn - 1));
        const int r1 = __builtin_amdgcn_readfirstlane(min(max(y0i + 1, 0), Hn - 1));
        const __half2* rp0 = fb + (size_t)(r0 * Wn) * PAIRS;   // uniform row ptrs
        const __half2* rp1 = fb + (size_t)(r1 * Wn) * PAIRS;
#pragma unroll
        for (int j = 0; j < 11; ++j) {
            const __half2 t00 = (rp0 + xo0[j])[pi];   // uniform ptr + lane idx
            const __half2 t01 = (rp0 + xo1[j])[pi];
            const __half2 t10 = (rp1 + xo0[j])[pi];
            const __half2 t11 = (rp1 + xo1[j])[pi];
            const __half2 X0 = __hfma2(wxh[j], __hsub2(t01, t00), t00);
            const __half2 X1 = __hfma2(wxh[j], __hsub2(t11, t10), t10);
            const __half2 s  = __hfma2(wyh,    __hsub2(X1,  X0),  X0);
            if (j == 0)      { dst[0] = s; }
            else if (j & 1)  { dst[j >> 1] = hmax2(dst[j >> 1], s); }
            else {
                dst[(j >> 1) - 1] = hmax2(dst[(j >> 1) - 1], s);
                if (j < 10) dst[j >> 1] = s;
            }
        }
    };

    __half2 prev[5], o2[25];
    dorow(0, prev);
#pragma unroll
    for (int ph = 0; ph < 5; ++ph) {
        __half2 tt[5], nxt[5];
        dorow(2 * ph + 1, tt);
        dorow(2 * ph + 2, nxt);
#pragma unroll
        for (int pw = 0; pw < 5; ++pw) {
            o2[ph * 5 + pw] = hmax2(hmax2(prev[pw], tt[pw]), nxt[pw]);
            prev[pw] = nxt[pw];
        }
    }

    float* stw = stage[wid];
    float* stl = &stw[lane * 25];

    // phase A: lo channels (wid*64..+63) -> contiguous 1600-float out block
#pragma unroll
    for (int p = 0; p < 25; ++p)
        stl[p] = __low2float(o2[p]);
    asm volatile("" ::: "memory");            // same-wave LDS in-order; pin ordering
    float* obl = out + (size_t)k * (Cn * 25) + (size_t)wid * 1600;
#pragma unroll
    for (int i = 0; i < 25; ++i)
        obl[i * 64 + lane] = stw[i * 64 + lane];

    // phase B: hi channels (+128) -> out block at +3200 floats
    asm volatile("" ::: "memory");
#pragma unroll
    for (int p = 0; p < 25; ++p)
        stl[p] = __high2float(o2[p]);
    asm volatile("" ::: "memory");
    float* obh = obl + 3200;
#pragma unroll
    for (int i = 0; i < 25; ++i)
        obh[i * 64 + lane] = stw[i * 64 + lane];
}

// ------------- Fallback (reads NCHW directly) if workspace too small -------------
__global__ __launch_bounds__(256)
void roialign_pool_fallback(const float* __restrict__ feats,
                            const float* __restrict__ rois,
                            float* __restrict__ out)
{
    __shared__ float smem[4][2][128];
    const int k    = blockIdx.x;
    const int tid  = threadIdx.x;
    const int wid  = tid >> 6;
    const int lane = tid & 63;

    const float x1 = rois[k * 5 + 1] * SCALE;
    const float y1 = rois[k * 5 + 2] * SCALE;
    const float x2 = rois[k * 5 + 3] * SCALE;
    const float y2 = rois[k * 5 + 4] * SCALE;
    const int   b  = (int)rois[k * 5 + 0];

    const int  p1   = 64 + lane;
    const bool act1 = (p1 < 121);
    int   o00[2], o01[2], o10[2], o11[2];
    float w00[2], w01[2], w10[2], w11[2];
#pragma unroll
    for (int r = 0; r < 2; ++r) {
        const int p  = (r == 0) ? lane : (act1 ? p1 : 120);
        const int gy = p / 11;
        const int gx = p - gy * 11;
        const float ys = y1 + (y2 - y1) * ((float)gy / 10.0f);
        const float xs = x1 + (x2 - x1) * ((float)gx / 10.0f);
        const float y0f = floorf(ys), x0f = floorf(xs);
        const float wy = ys - y0f, wxx = xs - x0f;
        const int y0i = (int)y0f, x0i = (int)x0f;
        const int y0c = min(max(y0i, 0), Hn - 1), y1c = min(max(y0i + 1, 0), Hn - 1);
        const int x0c = min(max(x0i, 0), Wn - 1), x1c = min(max(x0i + 1, 0), Wn - 1);
        o00[r] = y0c * Wn + x0c; o01[r] = y0c * Wn + x1c;
        o10[r] = y1c * Wn + x0c; o11[r] = y1c * Wn + x1c;
        w00[r] = (1.0f - wy) * (1.0f - wxx); w01[r] = (1.0f - wy) * wxx;
        w10[r] = wy * (1.0f - wxx);          w11[r] = wy * wxx;
    }
    const bool pool  = (lane < 25);
    const int  ph    = lane / 5;
    const int  pw    = lane - ph * 5;
    const int  pbase = (2 * ph) * 11 + 2 * pw;
    const float* base = feats + ((size_t)b * Cn + (size_t)wid * 64) * HWn;
    float*       op   = out + ((size_t)k * Cn + (size_t)wid * 64) * 25 + lane;
    for (int it = 0; it < 64; ++it) {
        const float* ff  = base + (size_t)it * HWn;
        float*       buf = smem[wid][it & 1];
        const float v0 = ff[o00[0]] * w00[0] + ff[o01[0]] * w01[0]
                       + ff[o10[0]] * w10[0] + ff[o11[0]] * w11[0];
        const float v1 = ff[o00[1]] * w00[1] + ff[o01[1]] * w01[1]
                       + ff[o10[1]] * w10[1] + ff[o11[1]] * w11[1];
        buf[lane] = v0;
        if (act1) buf[p1] = v1;
        if (pool) {
            float m =          buf[pbase +  0];
            m = fmaxf(m, buf[pbase +  1]);
            m = fmaxf(m, buf[pbase +  2]);
            m = fmaxf(m, buf[pbase + 11]);
            m = fmaxf(m, buf[pbase + 12]);
            m = fmaxf(m, buf[pbase + 13]);
            m = fmaxf(m, buf[pbase + 22]);
            m = fmaxf(m, buf[pbase + 23]);
            m = fmaxf(m, buf[pbase + 24]);
            op[it * 25] = m;
        }
    }
}

extern "C" void kernel_launch(void* const* d_in, const int* in_sizes, int n_in,
                              void* d_out, int out_size, void* d_ws, size_t ws_size,
                              hipStream_t stream) {
    const float* feats = (const float*)d_in[0];
    const float* rois  = (const float*)d_in[1];
    float*       out   = (float*)d_out;
    const int K = in_sizes[1] / 5;                                  // 2048
    const size_t need = (size_t)Bn * HWn * PAIRS * sizeof(unsigned int);  // 20.48 MB

    if (ws_size >= need) {
        unsigned int* nhwc = (unsigned int*)d_ws;
        dim3 tgrid((HWn + 63) / 64, PAIRS / 32, Bn);                // 157 x 4 x 4
        nchw_to_nhwc_f16<<<tgrid, 256, 0, stream>>>(feats, nhwc);
        roipool_half<<<K, 128, 0, stream>>>((const __half2*)d_ws, rois, out);
    } else {
        roialign_pool_fallback<<<K, 256, 0, stream>>>(feats, rois, out);
    }
}